// Round 4
// baseline (193.030 us; speedup 1.0000x reference)
//
#include <hip/hip_runtime.h>
#include <cmath>

#define DEV __device__ __forceinline__

static DEV float fast_exp2(float x) { return __builtin_amdgcn_exp2f(x); }
static DEV float fast_rcp(float x) { return __builtin_amdgcn_rcpf(x); }

#define LOG2E 1.4426950408889634f

static DEV float bperf(int addr, float v) {
  return __int_as_float(__builtin_amdgcn_ds_bpermute(addr, __float_as_int(v)));
}
static DEV int bperi(int addr, int v) {
  return __builtin_amdgcn_ds_bpermute(addr, v);
}
// swap adjacent lanes (2k <-> 2k+1) via DPP quad_perm [1,0,3,2]
static DEV float swapadj(float x) {
  return __int_as_float(
      __builtin_amdgcn_update_dpp(0, __float_as_int(x), 0xB1, 0xF, 0xF, true));
}

struct KP {
  const float* tags; const float* lem;
  const float* eWih0; const float* eWhh0; const float* ebih0; const float* ebhh0;
  const float* eWih1; const float* eWhh1; const float* ebih1; const float* ebhh1;
  const float* eWih2; const float* eWhh2; const float* ebih2; const float* ebhh2;
  const float* dWih0; const float* dWhh0; const float* dbih0; const float* dbhh0;
  const float* dWih1; const float* dWhh1; const float* dbih1; const float* dbhh1;
  const float* dWih2; const float* dWhh2; const float* dbih2; const float* dbhh2;
  const float* linW; const float* linb;
  float* outp; float* outt;
  int B;
};

// 3 chains per wave, 20 lanes per chain (lanes 60..63 duplicate lane 59).
// Within a chain group: lane sub = 2j+p owns gate rows:
//   p=0 -> (i_j, g_j) = rows (j, 20+j);  p=1 -> (f_j, o_j) = rows (10+j, 30+j).
// c_j and h_j are computed on the even lane of each pair; h broadcast by
// ds_bpermute. 12 chains per 256-thread block.
__global__ __launch_bounds__(256) void seq2seq_kernel(KP P) {
  const int tid = threadIdx.x;
  const int lane = tid & 63;

  // --- stage linW (+bias at slot 10) into LDS: row r -> [(r%20)][r/20][12] ---
  __shared__ __align__(16) float slin[20 * 60];
  for (int i = tid; i < 1100; i += 256) {
    if (i < 1000) {
      int r = i / 10, q = i - r * 10;
      slin[(r % 20) * 60 + (r / 20) * 12 + q] = P.linW[i];
    } else {
      int r = i - 1000;
      slin[(r % 20) * 60 + (r / 20) * 12 + 10] = P.linb[r];
    }
  }
  __syncthreads();

  int c = lane / 20; if (c > 2) c = 2;
  int sub = lane - c * 20; if (sub > 19) sub = 19;
  int b = blockIdx.x * 12 + (tid >> 6) * 3 + c;
  bool valid = (b < P.B); if (!valid) b = P.B - 1;
  const bool wr = (lane < 60) && valid;
  const int j = sub >> 1, p = sub & 1;
  const int rA = p ? 10 + j : j;        // sigmoid-gate row (i or f)
  const int rB = p ? 30 + j : 20 + j;   // g~ (even) or o (odd) row
  const int gb4 = c * 80;               // group-base lane * 4

  // row-B activation: even -> tanh, odd -> sigmoid
  const float kcB = p ? -LOG2E : -2.0f * LOG2E;
  const float amB = p ? 1.0f : 2.0f;
  const float abB = p ? 0.0f : -1.0f;

  // --- fold tag contribution into layer-0 pre-activations (enc + dec) ---
  float q0A = P.ebih0[rA] + P.ebhh0[rA];
  float q0B = P.ebih0[rB] + P.ebhh0[rB];
  float d0A = P.dbih0[rA] + P.dbhh0[rA];
  float d0B = P.dbih0[rB] + P.dbhh0[rB];
  float w0cA, w0cB, w0cAd, w0cBd;
  {
    const float4* eA = (const float4*)P.eWih0 + rA * 16;
    const float4* eB = (const float4*)P.eWih0 + rB * 16;
    const float4* dA = (const float4*)P.dWih0 + rA * 16;
    const float4* dB = (const float4*)P.dWih0 + rB * 16;
    const float* tg = P.tags + (size_t)b * 63;
    float4 a = eA[0], e = eB[0], f = dA[0], g = dB[0];
    w0cA = a.x; w0cB = e.x; w0cAd = f.x; w0cBd = g.x;
    float t0 = tg[0], t1 = tg[1], t2 = tg[2];
    q0A = fmaf(a.y, t0, q0A); q0A = fmaf(a.z, t1, q0A); q0A = fmaf(a.w, t2, q0A);
    q0B = fmaf(e.y, t0, q0B); q0B = fmaf(e.z, t1, q0B); q0B = fmaf(e.w, t2, q0B);
    d0A = fmaf(f.y, t0, d0A); d0A = fmaf(f.z, t1, d0A); d0A = fmaf(f.w, t2, d0A);
    d0B = fmaf(g.y, t0, d0B); d0B = fmaf(g.z, t1, d0B); d0B = fmaf(g.w, t2, d0B);
#pragma unroll
    for (int k = 1; k < 16; k++) {
      float4 a2 = eA[k], e2 = eB[k], f2 = dA[k], g2 = dB[k];
      float u0 = tg[4 * k - 1], u1 = tg[4 * k], u2 = tg[4 * k + 1], u3 = tg[4 * k + 2];
      q0A = fmaf(a2.x, u0, q0A); q0A = fmaf(a2.y, u1, q0A);
      q0A = fmaf(a2.z, u2, q0A); q0A = fmaf(a2.w, u3, q0A);
      q0B = fmaf(e2.x, u0, q0B); q0B = fmaf(e2.y, u1, q0B);
      q0B = fmaf(e2.z, u2, q0B); q0B = fmaf(e2.w, u3, q0B);
      d0A = fmaf(f2.x, u0, d0A); d0A = fmaf(f2.y, u1, d0A);
      d0A = fmaf(f2.z, u2, d0A); d0A = fmaf(f2.w, u3, d0A);
      d0B = fmaf(g2.x, u0, d0B); d0B = fmaf(g2.y, u1, d0B);
      d0B = fmaf(g2.z, u2, d0B); d0B = fmaf(g2.w, u3, d0B);
    }
  }

  // --- LSTM weight registers (encoder first; overwritten with decoder later) ---
  float wh0A[10], wh0B[10], wi1A[10], wi1B[10], wh1A[10], wh1B[10];
  float wi2A[10], wi2B[10], wh2A[10], wh2B[10];
#pragma unroll
  for (int q = 0; q < 10; q++) {
    wh0A[q] = P.eWhh0[rA * 10 + q]; wh0B[q] = P.eWhh0[rB * 10 + q];
    wi1A[q] = P.eWih1[rA * 10 + q]; wi1B[q] = P.eWih1[rB * 10 + q];
    wh1A[q] = P.eWhh1[rA * 10 + q]; wh1B[q] = P.eWhh1[rB * 10 + q];
    wi2A[q] = P.eWih2[rA * 10 + q]; wi2B[q] = P.eWih2[rB * 10 + q];
    wh2A[q] = P.eWhh2[rA * 10 + q]; wh2B[q] = P.eWhh2[rB * 10 + q];
  }
  float q1A = P.ebih1[rA] + P.ebhh1[rA], q1B = P.ebih1[rB] + P.ebhh1[rB];
  float q2A = P.ebih2[rA] + P.ebhh2[rA], q2B = P.ebih2[rB] + P.ebhh2[rB];

  float h0[10], h1[10], h2[10];
#pragma unroll
  for (int q = 0; q < 10; q++) { h0[q] = 0.0f; h1[q] = 0.0f; h2[q] = 0.0f; }
  float c0 = 0.0f, c1 = 0.0f, c2 = 0.0f;

  // gate pair -> state update; h_j lands on even lanes, broadcast to group
  auto upd = [&](float gA, float gB, float& cc, float (&h)[10]) {
    float aA = fast_rcp(1.0f + fast_exp2(gA * (-LOG2E)));  // sig(i) / sig(f)
    float yB = fast_rcp(1.0f + fast_exp2(gB * kcB));
    float aB = fmaf(amB, yB, abB);                         // tanh(g) / sig(o)
    float fsw = swapadj(aA);   // on even lanes: sig(f)
    float osw = swapadj(aB);   // on even lanes: sig(o)
    cc = fmaf(fsw, cc, aA * aB);                 // even: sig(f)*c + sig(i)*tanh(g)
    float y2 = fast_rcp(1.0f + fast_exp2(cc * (-2.0f * LOG2E)));
    float hv = osw * fmaf(2.0f, y2, -1.0f);      // even: sig(o)*tanh(c)
#pragma unroll
    for (int q = 0; q < 10; q++) h[q] = bperf(gb4 + q * 8, hv);
  };

  auto step = [&](float x) {
    float gA = fmaf(w0cA, x, q0A), gB = fmaf(w0cB, x, q0B);
#pragma unroll
    for (int q = 0; q < 10; q++) { gA = fmaf(wh0A[q], h0[q], gA); gB = fmaf(wh0B[q], h0[q], gB); }
    upd(gA, gB, c0, h0);
    gA = q1A; gB = q1B;
#pragma unroll
    for (int q = 0; q < 10; q++) { gA = fmaf(wi1A[q], h0[q], gA); gB = fmaf(wi1B[q], h0[q], gB); }
#pragma unroll
    for (int q = 0; q < 10; q++) { gA = fmaf(wh1A[q], h1[q], gA); gB = fmaf(wh1B[q], h1[q], gB); }
    upd(gA, gB, c1, h1);
    gA = q2A; gB = q2B;
#pragma unroll
    for (int q = 0; q < 10; q++) { gA = fmaf(wi2A[q], h1[q], gA); gB = fmaf(wi2B[q], h1[q], gB); }
#pragma unroll
    for (int q = 0; q < 10; q++) { gA = fmaf(wh2A[q], h2[q], gA); gB = fmaf(wh2B[q], h2[q], gB); }
    upd(gA, gB, c2, h2);
  };

  // ---------------- encoder: 32 steps ----------------
  float l1v = P.lem[(size_t)b * 32 + sub];
  float l2v = (sub < 12) ? P.lem[(size_t)b * 32 + 20 + sub] : 0.0f;
  for (int t = 0; t < 20; t++) step(bperf(gb4 + t * 4, l1v));
  for (int t = 0; t < 12; t++) step(bperf(gb4 + t * 4, l2v));

  // --- swap in decoder weights (same registers -> no extra VGPR pressure) ---
#pragma unroll
  for (int q = 0; q < 10; q++) {
    wh0A[q] = P.dWhh0[rA * 10 + q]; wh0B[q] = P.dWhh0[rB * 10 + q];
    wi1A[q] = P.dWih1[rA * 10 + q]; wi1B[q] = P.dWih1[rB * 10 + q];
    wh1A[q] = P.dWhh1[rA * 10 + q]; wh1B[q] = P.dWhh1[rB * 10 + q];
    wi2A[q] = P.dWih2[rA * 10 + q]; wi2B[q] = P.dWih2[rB * 10 + q];
    wh2A[q] = P.dWhh2[rA * 10 + q]; wh2B[q] = P.dWhh2[rB * 10 + q];
  }
  q0A = d0A; q0B = d0B; w0cA = w0cAd; w0cB = w0cBd;
  q1A = P.dbih1[rA] + P.dbhh1[rA]; q1B = P.dbih1[rB] + P.dbhh1[rB];
  q2A = P.dbih2[rA] + P.dbhh2[rA]; q2B = P.dbih2[rB] + P.dbhh2[rB];

  float* op0 = P.outp + (size_t)b * 3000 + sub;
  float tok = 1.0f;  // START

  // ---------------- decoder: 30 steps ----------------
  for (int st = 0; st < 30; st++) {
    step(tok);

    // linear: lane sub owns rows {sub, sub+20, ..., sub+80}; weights from LDS
    const float* lp = &slin[sub * 60];
    float pp[5];
#pragma unroll
    for (int k = 0; k < 5; k++) {
      const float4* w4 = (const float4*)(lp + k * 12);
      float4 w0 = w4[0], w1 = w4[1], w2 = w4[2];  // w2 = {w8, w9, bias, pad}
      float za = w2.z, zb = 0.0f;
      za = fmaf(w0.x, h2[0], za); zb = fmaf(w0.y, h2[1], zb);
      za = fmaf(w0.z, h2[2], za); zb = fmaf(w0.w, h2[3], zb);
      za = fmaf(w1.x, h2[4], za); zb = fmaf(w1.y, h2[5], zb);
      za = fmaf(w1.z, h2[6], za); zb = fmaf(w1.w, h2[7], zb);
      za = fmaf(w2.x, h2[8], za); zb = fmaf(w2.y, h2[9], zb);
      pp[k] = fast_rcp(1.0f + fast_exp2((za + zb) * (-LOG2E)));
    }

    if (wr) {
      float* op = op0 + st * 100;
      op[0] = pp[0]; op[20] = pp[1]; op[40] = pp[2]; op[60] = pp[3]; op[80] = pp[4];
    }

    // argmax (first-occurrence): local max -> ring max, local first idx -> ring min
    float vm = pp[0];
#pragma unroll
    for (int k = 1; k < 5; k++) vm = fmaxf(vm, pp[k]);
#pragma unroll
    for (int o = 1; o < 20; o <<= 1) {
      int t = sub + o; if (t >= 20) t -= 20;
      vm = fmaxf(vm, bperf(gb4 + t * 4, vm));
    }
    int il = 1000;
#pragma unroll
    for (int k = 4; k >= 0; k--) il = (pp[k] == vm) ? (sub + 20 * k) : il;
#pragma unroll
    for (int o = 1; o < 20; o <<= 1) {
      int t = sub + o; if (t >= 20) t -= 20;
      int io = bperi(gb4 + t * 4, il);
      il = (io < il) ? io : il;
    }
    tok = (float)il;
    if (wr && sub == 0) P.outt[(size_t)b * 30 + st] = tok;
  }
}

extern "C" void kernel_launch(void* const* d_in, const int* in_sizes, int n_in,
                              void* d_out, int out_size, void* d_ws, size_t ws_size,
                              hipStream_t stream) {
  KP P;
  P.tags = (const float*)d_in[2];
  P.lem = (const float*)d_in[3];
  P.eWih0 = (const float*)d_in[4];  P.eWhh0 = (const float*)d_in[5];
  P.ebih0 = (const float*)d_in[6];  P.ebhh0 = (const float*)d_in[7];
  P.eWih1 = (const float*)d_in[8];  P.eWhh1 = (const float*)d_in[9];
  P.ebih1 = (const float*)d_in[10]; P.ebhh1 = (const float*)d_in[11];
  P.eWih2 = (const float*)d_in[12]; P.eWhh2 = (const float*)d_in[13];
  P.ebih2 = (const float*)d_in[14]; P.ebhh2 = (const float*)d_in[15];
  P.dWih0 = (const float*)d_in[16]; P.dWhh0 = (const float*)d_in[17];
  P.dbih0 = (const float*)d_in[18]; P.dbhh0 = (const float*)d_in[19];
  P.dWih1 = (const float*)d_in[20]; P.dWhh1 = (const float*)d_in[21];
  P.dbih1 = (const float*)d_in[22]; P.dbhh1 = (const float*)d_in[23];
  P.dWih2 = (const float*)d_in[24]; P.dWhh2 = (const float*)d_in[25];
  P.dbih2 = (const float*)d_in[26]; P.dbhh2 = (const float*)d_in[27];
  P.linW = (const float*)d_in[28];
  P.linb = (const float*)d_in[29];

  const int B = in_sizes[3] / 32;  // lemmata is (B, 32)
  P.B = B;
  P.outp = (float*)d_out;
  P.outt = P.outp + (size_t)B * 3000;

  const int blocks = (B + 11) / 12;  // 12 chains per 256-thread block
  seq2seq_kernel<<<dim3(blocks), dim3(256), 0, stream>>>(P);
}

// Round 5
// 155.645 us; speedup vs baseline: 1.2402x; 1.2402x over previous
//
#include <hip/hip_runtime.h>
#include <cmath>
#include <stdint.h>

#define DEV __device__ __forceinline__

typedef float v2f __attribute__((ext_vector_type(2)));

static DEV float fast_exp2(float x) { return __builtin_amdgcn_exp2f(x); }
static DEV float fast_rcp(float x) { return __builtin_amdgcn_rcpf(x); }

#define LOG2E 1.4426950408889634f

static DEV float rdl(float x, int l) {
  return __int_as_float(__builtin_amdgcn_readlane(__float_as_int(x), l));
}
static DEV int rdli(float x, int l) {
  return __builtin_amdgcn_readlane(__float_as_int(x), l);
}
// pack two wave-uniform floats into one 64-bit scalar (SALU, off the VALU pipe)
static DEV uint64_t pack2(int lo, int hi) {
  return ((uint64_t)(uint32_t)hi << 32) | (uint32_t)lo;
}

// packed fp32 FMA: acc.{lo,hi} += w.{lo,hi} * h.{lo,hi}; h is an SGPR pair.
static DEV void pkfma(v2f& acc, v2f w, uint64_t h) {
  asm("v_pk_fma_f32 %0, %1, %2, %0" : "+v"(acc) : "v"(w), "s"(h));
}

// broadcast the value held by lane (4j+K) to all lanes of quad j (DPP quad_perm)
template <int K>
static DEV float qb(float x) {
  return __int_as_float(
      __builtin_amdgcn_update_dpp(0, __float_as_int(x), K * 0x55, 0xF, 0xF, true));
}

// m = max(m, dpp_shift(m)); bound_ctrl=true -> invalid lanes read 0.0f,
// safe as identity since all our probabilities are >= 0.
template <int CTRL>
static DEV float dppmax(float x) {
  float o = __int_as_float(
      __builtin_amdgcn_update_dpp(0, __float_as_int(x), CTRL, 0xF, 0xF, true));
  return fmaxf(x, o);
}

// full wave64 max via DPP (VALU only, no LDS): row_shr 1,2,4,8 then
// row_bcast15, row_bcast31; lane 63 holds the wave max.
static DEV float wavemax_bcast(float m) {
  m = dppmax<0x111>(m);
  m = dppmax<0x112>(m);
  m = dppmax<0x114>(m);
  m = dppmax<0x118>(m);
  m = dppmax<0x142>(m);  // row_bcast:15
  m = dppmax<0x143>(m);  // row_bcast:31
  return rdl(m, 63);
}

struct KP {
  const float* tags; const float* lem;
  const float* eWih0; const float* eWhh0; const float* ebih0; const float* ebhh0;
  const float* eWih1; const float* eWhh1; const float* ebih1; const float* ebhh1;
  const float* eWih2; const float* eWhh2; const float* ebih2; const float* ebhh2;
  const float* dWih0; const float* dWhh0; const float* dbih0; const float* dbhh0;
  const float* dWih1; const float* dWhh1; const float* dbih1; const float* dbhh1;
  const float* dWih2; const float* dWhh2; const float* dbih2; const float* dbhh2;
  const float* linW; const float* linb;
  float* outp; float* outt;
  int B;
};

// One wave (64 lanes) per batch chain. 4 chains per 256-thread block. No LDS.
// lane = 4*j + k : lane owns gate row (k*10 + j); k: 0=i, 1=f, 2=g~, 3=o.
// Lanes 40..63 (j>=10) are clamped to j=9 and compute harmless duplicates.
// Dot products use v_pk_fma_f32 (2 FMA/lane/instr): weights in VGPR pairs,
// h replicated as SGPR 64-bit pairs built from readlane results.
__global__ __launch_bounds__(256) void seq2seq_kernel(KP P) {
  const int tid = threadIdx.x;
  const int lane = tid & 63;
  const int b = blockIdx.x * 4 + (tid >> 6);
  if (b >= P.B) return;

  const int jq = lane >> 2;
  const int kg = lane & 3;
  const int jj = (jq < 10) ? jq : 9;
  const int row = kg * 10 + jj;

  // unified activation: sigmoid for i,f,o; tanh (=2*sigmoid(2x)-1) for g~
  const float kc = (kg == 2) ? (-2.0f * LOG2E) : (-LOG2E);
  const float am = (kg == 2) ? 2.0f : 1.0f;
  const float ab = (kg == 2) ? -1.0f : 0.0f;

  auto act = [&](float g) -> float {
    float y = fast_rcp(1.0f + fast_exp2(g * kc));
    return fmaf(am, y, ab);
  };

  // per-chain uniform data
  float tv = (lane < 63) ? P.tags[(size_t)b * 63 + lane] : 0.0f;
  float lemv = (lane < 32) ? P.lem[(size_t)b * 32 + lane] : 0.0f;

  // --- fold the (time-constant) tag contribution into the layer-0 biases ---
  // row of W_ih0 = 64 floats = 16 aligned float4s; element 0 is the char col.
  float pre0 = P.ebih0[row] + P.ebhh0[row];
  float dpre0 = P.dbih0[row] + P.dbhh0[row];
  float ew0c, dw0c;
  {
    const float4* e4 = (const float4*)P.eWih0 + row * 16;
    const float4* d4 = (const float4*)P.dWih0 + row * 16;
    float4 we = e4[0], wd = d4[0];
    ew0c = we.x; dw0c = wd.x;
    float t0 = rdl(tv, 0), t1 = rdl(tv, 1), t2 = rdl(tv, 2);
    pre0 = fmaf(we.y, t0, pre0); pre0 = fmaf(we.z, t1, pre0); pre0 = fmaf(we.w, t2, pre0);
    dpre0 = fmaf(wd.y, t0, dpre0); dpre0 = fmaf(wd.z, t1, dpre0); dpre0 = fmaf(wd.w, t2, dpre0);
#pragma unroll
    for (int c = 1; c < 16; c++) {
      float4 e = e4[c], d = d4[c];
      int dd = 4 * c - 1;
      float u0 = rdl(tv, dd), u1 = rdl(tv, dd + 1), u2 = rdl(tv, dd + 2), u3 = rdl(tv, dd + 3);
      pre0 = fmaf(e.x, u0, pre0); pre0 = fmaf(e.y, u1, pre0);
      pre0 = fmaf(e.z, u2, pre0); pre0 = fmaf(e.w, u3, pre0);
      dpre0 = fmaf(d.x, u0, dpre0); dpre0 = fmaf(d.y, u1, dpre0);
      dpre0 = fmaf(d.z, u2, dpre0); dpre0 = fmaf(d.w, u3, dpre0);
    }
  }

  // --- encoder weights as VGPR pairs (lane holds its gate row, 5 v2f each) ---
  v2f ehh0[5], eih1[5], ehh1[5], eih2[5], ehh2[5];
  {
    const v2f* a0 = (const v2f*)(P.eWhh0 + row * 10);
    const v2f* a1 = (const v2f*)(P.eWih1 + row * 10);
    const v2f* a2 = (const v2f*)(P.eWhh1 + row * 10);
    const v2f* a3 = (const v2f*)(P.eWih2 + row * 10);
    const v2f* a4 = (const v2f*)(P.eWhh2 + row * 10);
#pragma unroll
    for (int q = 0; q < 5; q++) {
      ehh0[q] = a0[q]; eih1[q] = a1[q]; ehh1[q] = a2[q];
      eih2[q] = a3[q]; ehh2[q] = a4[q];
    }
  }
  float pre1 = P.ebih1[row] + P.ebhh1[row];
  float pre2 = P.ebih2[row] + P.ebhh2[row];

  // state: h replicated as SGPR pairs {h_{2j}, h_{2j+1}}; c lives per-quad
  uint64_t h0[5], h1[5], h2[5];
#pragma unroll
  for (int q = 0; q < 5; q++) { h0[q] = 0; h1[q] = 0; h2[q] = 0; }
  float c0 = 0.0f, c1 = 0.0f, c2 = 0.0f;

  auto upd = [&](float a, float& c, uint64_t (&h)[5]) {
    float a0 = qb<0>(a);  // sigmoid(i)
    float a1 = qb<1>(a);  // sigmoid(f)
    float a2 = qb<2>(a);  // tanh(g~)
    float a3 = qb<3>(a);  // sigmoid(o)
    c = fmaf(a1, c, a0 * a2);
    // tanh(c) = 2*sigmoid(2c)-1; exp2 over/underflow saturates correctly
    float y = fast_rcp(1.0f + fast_exp2(c * (-2.0f * LOG2E)));
    float hv = a3 * fmaf(2.0f, y, -1.0f);
#pragma unroll
    for (int q = 0; q < 5; q++) h[q] = pack2(rdli(hv, 8 * q), rdli(hv, 8 * q + 4));
  };

  auto step = [&](float x, const v2f (&wh0)[5], const v2f (&wi1)[5],
                  const v2f (&wh1)[5], const v2f (&wi2)[5], const v2f (&wh2)[5],
                  float w0c, float p0_, float p1_, float p2_) {
    v2f a{fmaf(w0c, x, p0_), 0.0f};
#pragma unroll
    for (int q = 0; q < 5; q++) pkfma(a, wh0[q], h0[q]);
    upd(act(a.x + a.y), c0, h0);

    v2f aa{p1_, 0.0f}, bb{0.0f, 0.0f};
#pragma unroll
    for (int q = 0; q < 5; q++) { pkfma(aa, wi1[q], h0[q]); pkfma(bb, wh1[q], h1[q]); }
    upd(act((aa.x + aa.y) + (bb.x + bb.y)), c1, h1);

    v2f cc_{p2_, 0.0f}, dd{0.0f, 0.0f};
#pragma unroll
    for (int q = 0; q < 5; q++) { pkfma(cc_, wi2[q], h1[q]); pkfma(dd, wh2[q], h2[q]); }
    upd(act((cc_.x + cc_.y) + (dd.x + dd.y)), c2, h2);
  };

  // ---------------- encoder: 32 steps ----------------
  for (int t = 0; t < 32; t++) {
    step(rdl(lemv, t), ehh0, eih1, ehh1, eih2, ehh2, ew0c, pre0, pre1, pre2);
  }

  // --- decoder weights overwrite the same registers (no extra pressure) ---
  {
    const v2f* a0 = (const v2f*)(P.dWhh0 + row * 10);
    const v2f* a1 = (const v2f*)(P.dWih1 + row * 10);
    const v2f* a2 = (const v2f*)(P.dWhh1 + row * 10);
    const v2f* a3 = (const v2f*)(P.dWih2 + row * 10);
    const v2f* a4 = (const v2f*)(P.dWhh2 + row * 10);
#pragma unroll
    for (int q = 0; q < 5; q++) {
      ehh0[q] = a0[q]; eih1[q] = a1[q]; ehh1[q] = a2[q];
      eih2[q] = a3[q]; ehh2[q] = a4[q];
    }
  }
  pre1 = P.dbih1[row] + P.dbhh1[row];
  pre2 = P.dbih2[row] + P.dbhh2[row];

  // linear layer: lane holds rows lane and (64+lane if lane<36), as pairs
  const int lr2 = (lane < 36) ? (64 + lane) : 99;
  v2f lw0[5], lw1[5];
  {
    const v2f* a0 = (const v2f*)(P.linW + lane * 10);
    const v2f* a1 = (const v2f*)(P.linW + lr2 * 10);
#pragma unroll
    for (int q = 0; q < 5; q++) { lw0[q] = a0[q]; lw1[q] = a1[q]; }
  }
  float lb0 = P.linb[lane];
  float lb1 = (lane < 36) ? P.linb[lr2] : -1e30f;

  float* op0 = P.outp + (size_t)b * 3000;
  float tok = 1.0f;   // START
  float tokv = 0.0f;  // lane s accumulates step-s token

  // ---------------- decoder: 30 steps ----------------
  for (int s = 0; s < 30; s++) {
    step(tok, ehh0, eih1, ehh1, eih2, ehh2, dw0c, dpre0, pre1, pre2);

    // linear + sigmoid (packed dots, hardware exp2/rcp)
    v2f za{lb0, 0.0f}, zb{lb1, 0.0f};
#pragma unroll
    for (int q = 0; q < 5; q++) { pkfma(za, lw0[q], h2[q]); pkfma(zb, lw1[q], h2[q]); }
    float z0 = za.x + za.y, z1 = zb.x + zb.y;
    float p0 = fast_rcp(1.0f + fast_exp2(z0 * (-LOG2E)));
    float p1 = fast_rcp(1.0f + fast_exp2(z1 * (-LOG2E)));  // lanes>=36: exactly 0

    float* op = op0 + s * 100;
    op[lane] = p0;
    if (lane < 36) op[64 + lane] = p1;

    // argmax, first-occurrence: DPP wave-max (VALU) + ballot/ctz (SALU).
    // fmax returns one of its inputs bitwise, so vm matches some p exactly.
    float vm = wavemax_bcast(fmaxf(p0, p1));
    unsigned long long m0 = __ballot(p0 == vm);
    unsigned long long m1 = __ballot(p1 == vm);
    int im = m0 ? (int)__builtin_ctzll(m0) : 64 + (int)__builtin_ctzll(m1);
    tok = (float)im;
    tokv = (lane == s) ? tok : tokv;
  }

  if (lane < 30) P.outt[(size_t)b * 30 + lane] = tokv;
}

extern "C" void kernel_launch(void* const* d_in, const int* in_sizes, int n_in,
                              void* d_out, int out_size, void* d_ws, size_t ws_size,
                              hipStream_t stream) {
  KP P;
  P.tags = (const float*)d_in[2];
  P.lem = (const float*)d_in[3];
  P.eWih0 = (const float*)d_in[4];  P.eWhh0 = (const float*)d_in[5];
  P.ebih0 = (const float*)d_in[6];  P.ebhh0 = (const float*)d_in[7];
  P.eWih1 = (const float*)d_in[8];  P.eWhh1 = (const float*)d_in[9];
  P.ebih1 = (const float*)d_in[10]; P.ebhh1 = (const float*)d_in[11];
  P.eWih2 = (const float*)d_in[12]; P.eWhh2 = (const float*)d_in[13];
  P.ebih2 = (const float*)d_in[14]; P.ebhh2 = (const float*)d_in[15];
  P.dWih0 = (const float*)d_in[16]; P.dWhh0 = (const float*)d_in[17];
  P.dbih0 = (const float*)d_in[18]; P.dbhh0 = (const float*)d_in[19];
  P.dWih1 = (const float*)d_in[20]; P.dWhh1 = (const float*)d_in[21];
  P.dbih1 = (const float*)d_in[22]; P.dbhh1 = (const float*)d_in[23];
  P.dWih2 = (const float*)d_in[24]; P.dWhh2 = (const float*)d_in[25];
  P.dbih2 = (const float*)d_in[26]; P.dbhh2 = (const float*)d_in[27];
  P.linW = (const float*)d_in[28];
  P.linb = (const float*)d_in[29];

  const int B = in_sizes[3] / 32;  // lemmata is (B, 32)
  P.B = B;
  P.outp = (float*)d_out;
  P.outt = P.outp + (size_t)B * 3000;

  const int blocks = (B + 3) / 4;  // 4 chains (waves) per 256-thread block
  seq2seq_kernel<<<dim3(blocks), dim3(256), 0, stream>>>(P);
}